// Round 3
// baseline (107.454 us; speedup 1.0000x reference)
//
#include <hip/hip_runtime.h>

// Problem constants (B=4, N=512, D_in=512, D_out=256), fp32 in/out.
constexpr int Bq   = 4;
constexpr int Nq   = 512;
constexpr int DIN  = 512;
constexpr int DOUT = 256;

typedef _Float16 h2  __attribute__((ext_vector_type(2)));
typedef _Float16 h4  __attribute__((ext_vector_type(4)));
typedef _Float16 h8  __attribute__((ext_vector_type(8)));
typedef float    f4v __attribute__((ext_vector_type(4)));

#if defined(__has_builtin) && __has_builtin(__builtin_amdgcn_fdot2)
__device__ __forceinline__ float fdot2f(h2 a, h2 b, float c) {
    return __builtin_amdgcn_fdot2(a, b, c, false);   // v_dot2_f32_f16
}
#else
__device__ __forceinline__ float fdot2f(h2 a, h2 b, float c) {
    return (float)a.x * (float)b.x + (float)a.y * (float)b.y + c;
}
#endif

__device__ __forceinline__ h8 cvt8(float4 lo, float4 hi) {
    h8 r;
    r[0] = (_Float16)lo.x; r[1] = (_Float16)lo.y;
    r[2] = (_Float16)lo.z; r[3] = (_Float16)lo.w;
    r[4] = (_Float16)hi.x; r[5] = (_Float16)hi.y;
    r[6] = (_Float16)hi.z; r[7] = (_Float16)hi.w;
    return r;
}

// ---------------------------------------------------------------------------
// K1: Wh = H @ W^T via MFMA 16x16x32 f16, fp32->fp16 conversion in-register.
// NEW: K-split by 2 — grid 1025 x 256 thr (4 waves). Waves (w&1)=tile,
// (w>>1)=K-half; partials combined through 2 KB LDS. Doubles wave count
// (2->4 per SIMD) and halves the latency-chained load depth.
// Epilogue (kh==0 waves): Wh16[n][o2], WhT16p[b][o2][j] (o-packed via
// shfl_xor 1) and NEW WhT16n[b][o][j2] (j-packed, one 8B store/lane) for
// k23's MFMA B-operand. fp32 Wh is no longer materialized at all.
// Block 1024 converts `a`.
// ---------------------------------------------------------------------------
__global__ __launch_bounds__(256) void k1_wh(const float* __restrict__ H,
                                             const float* __restrict__ W,
                                             const float* __restrict__ a,
                                             h2* __restrict__ Wh16,
                                             h2* __restrict__ WhT16p,
                                             h2* __restrict__ WhT16n,
                                             h2* __restrict__ a16) {
    const int bid = blockIdx.x;
    const int t   = threadIdx.x;

    if (bid == 1024) {                    // a conversion (tiny, one block)
        if (t < 64) {
            const int idx = 2 * t;        // h2 index (even)
            const float4 v = *(const float4*)&a[2 * idx];
            h2 h0; h0.x = (_Float16)v.x; h0.y = (_Float16)v.y;
            h2 h1; h1.x = (_Float16)v.z; h1.y = (_Float16)v.w;
            a16[idx] = h0; a16[idx + 1] = h1;
        }
        return;
    }

    const int w    = t >> 6;
    const int lane = t & 63;
    const int T    = (bid << 1) | (w & 1);   // global tile 0..2047
    const int kh   = w >> 1;                 // K-half 0/1
    const int mt   = T >> 4;                 // 0..127
    const int b    = mt & 3;
    const int n0   = (T >> 6) << 4;          // 0..496
    const int o0   = (T & 15) << 4;          // 0..240
    const int quad = lane >> 4;
    const int col  = lane & 15;

    // A: lane reads H row (n0+col) fp32, this K-half; B: W row (o0+col)
    const float4* __restrict__ aP =
        (const float4*)(H + (size_t)(b * Nq + n0 + col) * DIN) + kh * 64 + quad * 2;
    const float4* __restrict__ bP =
        (const float4*)(W + (size_t)(o0 + col) * DIN) + kh * 64 + quad * 2;

    f4v acc = {0.f, 0.f, 0.f, 0.f};
    float4 fa0 = aP[0], fa1 = aP[1];
    float4 fb0 = bP[0], fb1 = bP[1];

#pragma unroll
    for (int kb = 0; kb < 8; ++kb) {
        float4 na0 = fa0, na1 = fa1, nb0 = fb0, nb1 = fb1;
        if (kb < 7) {                     // depth-1 prefetch
            na0 = aP[(kb + 1) * 8];
            na1 = aP[(kb + 1) * 8 + 1];
            nb0 = bP[(kb + 1) * 8];
            nb1 = bP[(kb + 1) * 8 + 1];
        }
        const h8 af = cvt8(fa0, fa1);
        const h8 bf = cvt8(fb0, fb1);
        acc = __builtin_amdgcn_mfma_f32_16x16x32_f16(af, bf, acc, 0, 0, 0);
        fa0 = na0; fa1 = na1; fb0 = nb0; fb1 = nb1;
    }

    __shared__ f4v sPart[2][64];          // K-half combine, per tile-in-block
    if (kh) sPart[w & 1][lane] = acc;
    __syncthreads();
    if (!kh) {
        const f4v p = sPart[w & 1][lane];
#pragma unroll
        for (int r = 0; r < 4; ++r) acc[r] += p[r];

        const int rloc = n0 + quad * 4;   // local row (j) of reg 0

        // j-packed transpose store (MFMA B-operand for k23 phase B)
        h4 hj;
        hj[0] = (_Float16)acc[0]; hj[1] = (_Float16)acc[1];
        hj[2] = (_Float16)acc[2]; hj[3] = (_Float16)acc[3];
        *(h4*)(WhT16n + ((size_t)(b * 256 + o0 + col)) * 256 + (rloc >> 1)) = hj;

        // o-packed stores (phase A operands)
#pragma unroll
        for (int reg = 0; reg < 4; ++reg) {
            const float v  = acc[reg];
            const float vp = __shfl_xor(v, 1);    // partner o
            if ((col & 1) == 0) {
                h2 hv; hv.x = (_Float16)v; hv.y = (_Float16)vp;
                const int o2 = (o0 + col) >> 1;
                Wh16[(size_t)(b * Nq + rloc + reg) * 128 + o2] = hv;           // [n][o2]
                WhT16p[(size_t)b * 65536 + (size_t)o2 * 512 + (rloc + reg)] = hv;
            }
        }
    }
}

// ---------------------------------------------------------------------------
// K23: fused e+softmax (phase A) and out = P @ Wh (phase B).
// NEW this round: 8 i-rows per block, grid 256 = (b, 64 i-groups), 1024 thr.
// Phase A: same fp16 dot2 algorithm, extended to 8 rows (halves per-block
// re-fetch of WhT16p slices). Softmax packs normalized P to fp16 in LDS
// (sPh, stride 260 h2 to spread banks).
// Phase B: MFMA 16x16x32 f16. 16 waves x one 16-o tile, K=512 over j.
// A-frag from sPh rows (col&7; C rows 8..15 are don't-care, not stored),
// B-frag = 16B contiguous loads from WhT16n[o][j]. 16 MFMA/wave, depth-1
// prefetch on B. Phase-B L2 traffic 268->67 MB and VALU ~0.
// ---------------------------------------------------------------------------
__global__ __launch_bounds__(1024, 8) void k23(const h2* __restrict__ Wh16,
                                               const h2* __restrict__ WhT16p,
                                               const h2* __restrict__ WhT16n,
                                               const h2* __restrict__ a16,
                                               float* __restrict__ out) {
    const int t   = threadIdx.x;
    const int blk = blockIdx.x;           // 256
    const int b   = blk & 3;
    const int i0  = (blk >> 2) << 3;      // 8 i-rows

    __shared__ float smem[5120];          // sAb[8*512] + sRh[512] + sRf[512]
    __shared__ h2    sPh[8 * 260];        // packed P fp16, row stride 260 h2
    __shared__ float wred[2][8][8];

    // ======================= Phase A: e + softmax -> sPh ===================
    {
        const int h  = __builtin_amdgcn_readfirstlane(t >> 9);  // 0/1
        const int j  = t & 511;
        const int ob = h * 64;            // o2 base (64 o-pairs = 128 o)

        const h2* __restrict__ wjp = WhT16p + (size_t)b * 65536 + (size_t)ob * 512 + j;
        const h2* __restrict__ wip = Wh16 + (size_t)(b * Nq + i0) * 128;  // uniform

        float ab[8];
#pragma unroll
        for (int rr = 0; rr < 8; ++rr) ab[rr] = 0.f;
        float rja = 0.f;                  // this half's partial of r_j
        h2 cA[8], cB[8];

#define K2_L8(buf, kb)                                                      \
    _Pragma("unroll") for (int s = 0; s < 8; ++s)                           \
        buf[s] = wjp[((kb) + s) * 512];

#define K2_C8(buf, kb)                                                      \
    _Pragma("unroll") for (int s = 0; s < 8; ++s) {                         \
        const int o2 = ob + (kb) + s;                                       \
        const h2 a2 = a16[o2];                                  /* s_load */\
        rja = fdot2f(a2, buf[s], rja);                                      \
        _Pragma("unroll") for (int rr = 0; rr < 8; ++rr) {                  \
            const h2 wi = wip[rr * 128 + o2];                   /* s_load */\
            h2 w  = buf[s] + wi;                                /* pk_add */\
            h2 aw = __builtin_elementwise_max(w, -w);           /* pk_max */\
            ab[rr] = fdot2f(a2, aw, ab[rr]);                    /* dot2   */\
        }                                                                   \
    }

        K2_L8(cA, 0)  K2_L8(cB, 8)
        K2_C8(cA, 0)  K2_L8(cA, 16)
        K2_C8(cB, 8)  K2_L8(cB, 24)
        K2_C8(cA, 16) K2_L8(cA, 32)
        K2_C8(cB, 24) K2_L8(cB, 40)
        K2_C8(cA, 32) K2_L8(cA, 48)
        K2_C8(cB, 40) K2_L8(cB, 56)
        K2_C8(cA, 48)
        K2_C8(cB, 56)
#undef K2_L8
#undef K2_C8

        // combine halves: sAb[8][512] @ smem[0..4095], sRh @ [4096..4607],
        // final r @ [4608..5119]
        float* sAb = smem;
        float* sRh = smem + 4096;
        float* sRf = smem + 4608;
        if (h == 1) {
#pragma unroll
            for (int rr = 0; rr < 8; ++rr) sAb[rr * 512 + j] = ab[rr];
            sRh[j] = rja;
        }
        __syncthreads();

        float rj = 0.f;
        if (h == 0) {
#pragma unroll
            for (int rr = 0; rr < 8; ++rr) ab[rr] += sAb[rr * 512 + j];
            rj = rja + sRh[j];
            sRf[j] = rj;
        }
        __syncthreads();                  // sRf visible to all

        float e[8], pv[8];
        const int lane = t & 63;
        const int w    = t >> 6;          // h0: waves 0..7

        if (h == 0) {
#pragma unroll
            for (int rr = 0; rr < 8; ++rr)
                e[rr] = 0.6f * (sRf[i0 + rr] + rj) + 0.4f * ab[rr];
#pragma unroll
            for (int rr = 0; rr < 8; ++rr) {
                float v = e[rr];
#pragma unroll
                for (int off = 32; off > 0; off >>= 1) v = fmaxf(v, __shfl_xor(v, off));
                if (lane == 0) wred[0][rr][w] = v;
            }
        }
        __syncthreads();
        if (h == 0) {
#pragma unroll
            for (int rr = 0; rr < 8; ++rr) {
                const float4 q0 = *(const float4*)&wred[0][rr][0];
                const float4 q1 = *(const float4*)&wred[0][rr][4];
                const float m = fmaxf(fmaxf(fmaxf(q0.x, q0.y), fmaxf(q0.z, q0.w)),
                                      fmaxf(fmaxf(q1.x, q1.y), fmaxf(q1.z, q1.w)));
                pv[rr] = __expf(e[rr] - m);
            }
#pragma unroll
            for (int rr = 0; rr < 8; ++rr) {
                float v = pv[rr];
#pragma unroll
                for (int off = 32; off > 0; off >>= 1) v += __shfl_xor(v, off);
                if (lane == 0) wred[1][rr][w] = v;
            }
        }
        __syncthreads();
        if (h == 0) {
#pragma unroll
            for (int rr = 0; rr < 8; ++rr) {
                const float4 q0 = *(const float4*)&wred[1][rr][0];
                const float4 q1 = *(const float4*)&wred[1][rr][4];
                const float s = (q0.x + q0.y + q0.z + q0.w) + (q1.x + q1.y + q1.z + q1.w);
                const float pn = pv[rr] * (1.0f / s);
                const float pp = __shfl_xor(pn, 1);
                if ((j & 1) == 0) {
                    h2 hv; hv.x = (_Float16)pn; hv.y = (_Float16)pp;
                    sPh[rr * 260 + (j >> 1)] = hv;     // packed along j
                }
            }
        }
        __syncthreads();                  // sPh ready
    }

    // ======================= Phase B: out = P @ Wh (MFMA) ==================
    {
        const int w16  = __builtin_amdgcn_readfirstlane(t >> 6);  // 0..15
        const int lane = t & 63;
        const int quad = lane >> 4;
        const int col  = lane & 15;
        const int o0   = w16 << 4;        // this wave's 16-o tile

        // B-frag: WhT16n row (o0+col), k = kb*32 + quad*8 + i  (16B loads)
        const h2* __restrict__ wt =
            WhT16n + (size_t)b * 65536 + (size_t)(o0 + col) * 256 + quad * 4;
        // A-frag: packed P rows (col&7) — rows 8..15 of C are don't-care
        const h2* __restrict__ ap = sPh + (col & 7) * 260 + quad * 4;

        f4v acc = {0.f, 0.f, 0.f, 0.f};
        h8 b0 = *(const h8*)wt;
#pragma unroll
        for (int kb = 0; kb < 16; ++kb) {
            h8 b1 = b0;
            if (kb < 15) b1 = *(const h8*)(wt + (kb + 1) * 16);   // prefetch
            const h8 af = *(const h8*)(ap + kb * 16);             // ds_read_b128
            acc = __builtin_amdgcn_mfma_f32_16x16x32_f16(af, b0, acc, 0, 0, 0);
            b0 = b1;
        }

        if (quad < 2) {                   // C rows 0..7 (i), cols = o
#pragma unroll
            for (int reg = 0; reg < 4; ++reg) {
                const int row = quad * 4 + reg;
                out[((size_t)(b * Nq) + i0 + row) * DOUT + o0 + col] = acc[reg];
            }
        }
    }
}

// ---------------------------------------------------------------------------
extern "C" void kernel_launch(void* const* d_in, const int* in_sizes, int n_in,
                              void* d_out, int out_size, void* d_ws, size_t ws_size,
                              hipStream_t stream) {
    const float* H = (const float*)d_in[0];   // [4,512,512]
    const float* W = (const float*)d_in[1];   // [256,512]
    const float* a = (const float*)d_in[2];   // [256,1]
    float* out = (float*)d_out;               // [4,512,256]

    h2* Wh16   = (h2*)d_ws;                    // 262144 h2 (1 MB) [n][o2]
    h2* WhT16p = Wh16 + 262144;                // 262144 h2 (1 MB) [b][o2][j]
    h2* WhT16n = WhT16p + 262144;              // 262144 h2 (1 MB) [b][o][j2]
    h2* a16    = WhT16n + 262144;              // 128 h2

    hipLaunchKernelGGL(k1_wh, dim3(1025), dim3(256),  0, stream, H, W, a, Wh16, WhT16p, WhT16n, a16);
    hipLaunchKernelGGL(k23,   dim3(256),  dim3(1024), 0, stream, Wh16, WhT16p, WhT16n, a16, out);
}

// Round 4
// 106.967 us; speedup vs baseline: 1.0045x; 1.0045x over previous
//
#include <hip/hip_runtime.h>

// Problem constants (B=4, N=512, D_in=512, D_out=256), fp32 in/out.
constexpr int Bq   = 4;
constexpr int Nq   = 512;
constexpr int DIN  = 512;
constexpr int DOUT = 256;

typedef _Float16 h2  __attribute__((ext_vector_type(2)));
typedef _Float16 h4  __attribute__((ext_vector_type(4)));
typedef _Float16 h8  __attribute__((ext_vector_type(8)));
typedef float    f4v __attribute__((ext_vector_type(4)));

#if defined(__has_builtin) && __has_builtin(__builtin_amdgcn_fdot2)
__device__ __forceinline__ float fdot2f(h2 a, h2 b, float c) {
    return __builtin_amdgcn_fdot2(a, b, c, false);   // v_dot2_f32_f16
}
#else
__device__ __forceinline__ float fdot2f(h2 a, h2 b, float c) {
    return (float)a.x * (float)b.x + (float)a.y * (float)b.y + c;
}
#endif

__device__ __forceinline__ h8 cvt8(float4 lo, float4 hi) {
    h8 r;
    r[0] = (_Float16)lo.x; r[1] = (_Float16)lo.y;
    r[2] = (_Float16)lo.z; r[3] = (_Float16)lo.w;
    r[4] = (_Float16)hi.x; r[5] = (_Float16)hi.y;
    r[6] = (_Float16)hi.z; r[7] = (_Float16)hi.w;
    return r;
}

// ---------------------------------------------------------------------------
// K1: Wh = H @ W^T via MFMA 16x16x32 f16, fp32->fp16 conversion in-register.
// REVERTED to R2 structure: grid 513 x 256 thr (4 waves), one 16x16 tile per
// wave, 16-deep K loop, no LDS. (R3's K-split is unbundled out.)
// Epilogue: Wh16[n][o2] + WhT16p[b][o2][j] (o-packed via shfl_xor 1) and
// WhT16n[b][o][j2] (j-packed h4 store) for k23's MFMA B-operand. fp32 Wh is
// not materialized. Block 512 converts `a`.
// ---------------------------------------------------------------------------
__global__ __launch_bounds__(256) void k1_wh(const float* __restrict__ H,
                                             const float* __restrict__ W,
                                             const float* __restrict__ a,
                                             h2* __restrict__ Wh16,
                                             h2* __restrict__ WhT16p,
                                             h2* __restrict__ WhT16n,
                                             h2* __restrict__ a16) {
    const int bid = blockIdx.x;
    const int t   = threadIdx.x;

    if (bid == 512) {                     // a conversion (tiny, one block)
        if (t < 64) {
            const int idx = 2 * t;        // h2 index (even)
            const float4 v = *(const float4*)&a[2 * idx];
            h2 h0; h0.x = (_Float16)v.x; h0.y = (_Float16)v.y;
            h2 h1; h1.x = (_Float16)v.z; h1.y = (_Float16)v.w;
            a16[idx] = h0; a16[idx + 1] = h1;
        }
        return;
    }

    const int w    = t >> 6;
    const int lane = t & 63;
    const int mt   = bid >> 2;            // 0..127
    const int b    = mt & 3;              // XCD spread
    const int n0   = (mt >> 2) << 4;      // 0..496
    const int o0   = ((bid & 3) << 6) + (w << 4);
    const int quad = lane >> 4;
    const int col  = lane & 15;

    const float4* __restrict__ aP =
        (const float4*)(H + (size_t)(b * Nq + n0 + col) * DIN) + quad * 2;
    const float4* __restrict__ bP =
        (const float4*)(W + (size_t)(o0 + col) * DIN) + quad * 2;

    f4v acc = {0.f, 0.f, 0.f, 0.f};
    float4 fa0 = aP[0], fa1 = aP[1];
    float4 fb0 = bP[0], fb1 = bP[1];

#pragma unroll
    for (int kb = 0; kb < 16; ++kb) {
        float4 na0 = fa0, na1 = fa1, nb0 = fb0, nb1 = fb1;
        if (kb < 15) {                    // depth-1 prefetch (8 float4 / kb)
            na0 = aP[(kb + 1) * 8];
            na1 = aP[(kb + 1) * 8 + 1];
            nb0 = bP[(kb + 1) * 8];
            nb1 = bP[(kb + 1) * 8 + 1];
        }
        const h8 af = cvt8(fa0, fa1);
        const h8 bf = cvt8(fb0, fb1);
        acc = __builtin_amdgcn_mfma_f32_16x16x32_f16(af, bf, acc, 0, 0, 0);
        fa0 = na0; fa1 = na1; fb0 = nb0; fb1 = nb1;
    }

    const int rloc = n0 + quad * 4;       // local row (j) of reg 0

    // j-packed transpose store (MFMA B-operand for k23 phase B), 8B/lane
    h4 hj;
    hj[0] = (_Float16)acc[0]; hj[1] = (_Float16)acc[1];
    hj[2] = (_Float16)acc[2]; hj[3] = (_Float16)acc[3];
    *(h4*)(WhT16n + ((size_t)(b * 256 + o0 + col)) * 256 + (rloc >> 1)) = hj;

    // o-packed stores (phase A operands)
#pragma unroll
    for (int reg = 0; reg < 4; ++reg) {
        const float v  = acc[reg];
        const float vp = __shfl_xor(v, 1);     // partner o
        if ((col & 1) == 0) {
            h2 hv; hv.x = (_Float16)v; hv.y = (_Float16)vp;
            const int o2 = (o0 + col) >> 1;
            Wh16[(size_t)(b * Nq + rloc + reg) * 128 + o2] = hv;           // [n][o2]
            WhT16p[(size_t)b * 65536 + (size_t)o2 * 512 + (rloc + reg)] = hv;
        }
    }
}

// ---------------------------------------------------------------------------
// K23: fused e+softmax (phase A) and out = P @ Wh (phase B).
// Phase A: REVERTED to R2's 4 rows/block, grid 512, 1024 thr (2 blocks/CU =
// 32 waves/CU — R3's 8-row/256-block variant halved occupancy and regressed).
// Softmax now packs normalized P to fp16 in LDS (sPh, stride 272 h2 ->
// conflict-free replicated A-frag reads).
// Phase B: MFMA 16x16x32 f16 (kept from R3, adapted to 4 rows). 16 waves x
// one 16-o tile, K=512 over j. A-frag rows replicated (col&3); C rows 4..15
// are don't-care and not stored. B-frag = 16B contiguous loads of WhT16n.
// 16 MFMA/wave, depth-1 prefetch on B. Replaces 32 fp32-float4 L2 loads +
// 512 pk-FMAs + 2-barrier LDS reduce per lane.
// ---------------------------------------------------------------------------
__global__ __launch_bounds__(1024, 8) void k23(const h2* __restrict__ Wh16,
                                               const h2* __restrict__ WhT16p,
                                               const h2* __restrict__ WhT16n,
                                               const h2* __restrict__ a16,
                                               float* __restrict__ out) {
    const int t   = threadIdx.x;
    const int blk = blockIdx.x;           // 512
    const int b   = blk & 3;
    const int i0  = (blk >> 2) << 2;      // 4 i-rows

    __shared__ float smem[8192];          // 32 KB arena: sAb/sRh/sRf (A)
    __shared__ __align__(16) h2 sPh[4 * 272];   // packed P fp16, stride 272 h2
    __shared__ float wred[2][4][8];

    // ======================= Phase A: e + softmax -> sPh ===================
    {
        const int h  = __builtin_amdgcn_readfirstlane(t >> 9);  // 0/1
        const int j  = t & 511;
        const int ob = h * 64;            // o2 base (64 o-pairs = 128 o)

        const h2* __restrict__ wjp = WhT16p + (size_t)b * 65536 + (size_t)ob * 512 + j;
        const h2* __restrict__ wip = Wh16 + (size_t)(b * Nq + i0) * 128;  // uniform

        float ab[4] = {0.f, 0.f, 0.f, 0.f};
        float rja = 0.f;                  // this half's partial of r_j
        h2 cA[8], cB[8];

#define K2_L8(buf, kb)                                                      \
    _Pragma("unroll") for (int s = 0; s < 8; ++s)                           \
        buf[s] = wjp[((kb) + s) * 512];

#define K2_C8(buf, kb)                                                      \
    _Pragma("unroll") for (int s = 0; s < 8; ++s) {                         \
        const int o2 = ob + (kb) + s;                                       \
        const h2 a2 = a16[o2];                                  /* s_load */\
        rja = fdot2f(a2, buf[s], rja);                                      \
        _Pragma("unroll") for (int rr = 0; rr < 4; ++rr) {                  \
            const h2 wi = wip[rr * 128 + o2];                   /* s_load */\
            h2 w  = buf[s] + wi;                                /* pk_add */\
            h2 aw = __builtin_elementwise_max(w, -w);           /* pk_max */\
            ab[rr] = fdot2f(a2, aw, ab[rr]);                    /* dot2   */\
        }                                                                   \
    }

        K2_L8(cA, 0)  K2_L8(cB, 8)
        K2_C8(cA, 0)  K2_L8(cA, 16)
        K2_C8(cB, 8)  K2_L8(cB, 24)
        K2_C8(cA, 16) K2_L8(cA, 32)
        K2_C8(cB, 24) K2_L8(cB, 40)
        K2_C8(cA, 32) K2_L8(cA, 48)
        K2_C8(cB, 40) K2_L8(cB, 56)
        K2_C8(cA, 48)
        K2_C8(cB, 56)
#undef K2_L8
#undef K2_C8

        // combine halves: sAb[4][512] @ smem[0..2047], sRh @ [2048..2559],
        // final r @ [2560..3071]
        float* sAb = smem;
        float* sRh = smem + 2048;
        float* sRf = smem + 2560;
        if (h == 1) {
#pragma unroll
            for (int rr = 0; rr < 4; ++rr) sAb[rr * 512 + j] = ab[rr];
            sRh[j] = rja;
        }
        __syncthreads();

        float rj = 0.f;
        if (h == 0) {
#pragma unroll
            for (int rr = 0; rr < 4; ++rr) ab[rr] += sAb[rr * 512 + j];
            rj = rja + sRh[j];
            sRf[j] = rj;
        }
        __syncthreads();                  // sRf visible to all

        float e[4], pv[4];
        const int lane = t & 63;
        const int w    = t >> 6;          // h0: waves 0..7

        if (h == 0) {
#pragma unroll
            for (int rr = 0; rr < 4; ++rr)
                e[rr] = 0.6f * (sRf[i0 + rr] + rj) + 0.4f * ab[rr];
#pragma unroll
            for (int rr = 0; rr < 4; ++rr) {
                float v = e[rr];
#pragma unroll
                for (int off = 32; off > 0; off >>= 1) v = fmaxf(v, __shfl_xor(v, off));
                if (lane == 0) wred[0][rr][w] = v;
            }
        }
        __syncthreads();
        if (h == 0) {
#pragma unroll
            for (int rr = 0; rr < 4; ++rr) {
                const float4 q0 = *(const float4*)&wred[0][rr][0];
                const float4 q1 = *(const float4*)&wred[0][rr][4];
                const float m = fmaxf(fmaxf(fmaxf(q0.x, q0.y), fmaxf(q0.z, q0.w)),
                                      fmaxf(fmaxf(q1.x, q1.y), fmaxf(q1.z, q1.w)));
                pv[rr] = __expf(e[rr] - m);
            }
#pragma unroll
            for (int rr = 0; rr < 4; ++rr) {
                float v = pv[rr];
#pragma unroll
                for (int off = 32; off > 0; off >>= 1) v += __shfl_xor(v, off);
                if (lane == 0) wred[1][rr][w] = v;
            }
        }
        __syncthreads();
        if (h == 0) {
#pragma unroll
            for (int rr = 0; rr < 4; ++rr) {
                const float4 q0 = *(const float4*)&wred[1][rr][0];
                const float4 q1 = *(const float4*)&wred[1][rr][4];
                const float s = (q0.x + q0.y + q0.z + q0.w) + (q1.x + q1.y + q1.z + q1.w);
                const float pn = pv[rr] * (1.0f / s);
                const float pp = __shfl_xor(pn, 1);
                if ((j & 1) == 0) {
                    h2 hv; hv.x = (_Float16)pn; hv.y = (_Float16)pp;
                    sPh[rr * 272 + (j >> 1)] = hv;     // packed along j
                }
            }
        }
        __syncthreads();                  // sPh ready
    }

    // ======================= Phase B: out = P @ Wh (MFMA) ==================
    {
        const int w16  = __builtin_amdgcn_readfirstlane(t >> 6);  // 0..15
        const int lane = t & 63;
        const int quad = lane >> 4;
        const int col  = lane & 15;
        const int o0   = w16 << 4;        // this wave's 16-o tile

        // B-frag: WhT16n row (o0+col), j2 = kb*16 + quad*4 + [0..3] (16B loads)
        const h2* __restrict__ wt =
            WhT16n + (size_t)b * 65536 + (size_t)(o0 + col) * 256 + quad * 4;
        // A-frag: packed P rows replicated (col&3) — C rows 4..15 don't-care
        const h2* __restrict__ ap = sPh + (col & 3) * 272 + quad * 4;

        f4v acc = {0.f, 0.f, 0.f, 0.f};
        h8 b0 = *(const h8*)wt;
#pragma unroll
        for (int kb = 0; kb < 16; ++kb) {
            h8 b1 = b0;
            if (kb < 15) b1 = *(const h8*)(wt + (kb + 1) * 16);   // prefetch
            const h8 af = *(const h8*)(ap + kb * 16);             // ds_read_b128
            acc = __builtin_amdgcn_mfma_f32_16x16x32_f16(af, b0, acc, 0, 0, 0);
            b0 = b1;
        }

        if (quad == 0) {                  // C rows 0..3 (i), cols = o
#pragma unroll
            for (int reg = 0; reg < 4; ++reg) {
                out[((size_t)(b * Nq) + i0 + reg) * DOUT + o0 + col] = acc[reg];
            }
        }
    }
}

// ---------------------------------------------------------------------------
extern "C" void kernel_launch(void* const* d_in, const int* in_sizes, int n_in,
                              void* d_out, int out_size, void* d_ws, size_t ws_size,
                              hipStream_t stream) {
    const float* H = (const float*)d_in[0];   // [4,512,512]
    const float* W = (const float*)d_in[1];   // [256,512]
    const float* a = (const float*)d_in[2];   // [256,1]
    float* out = (float*)d_out;               // [4,512,256]

    h2* Wh16   = (h2*)d_ws;                    // 262144 h2 (1 MB) [n][o2]
    h2* WhT16p = Wh16 + 262144;                // 262144 h2 (1 MB) [b][o2][j]
    h2* WhT16n = WhT16p + 262144;              // 262144 h2 (1 MB) [b][o][j2]
    h2* a16    = WhT16n + 262144;              // 128 h2

    hipLaunchKernelGGL(k1_wh, dim3(513), dim3(256),  0, stream, H, W, a, Wh16, WhT16p, WhT16n, a16);
    hipLaunchKernelGGL(k23,   dim3(512), dim3(1024), 0, stream, Wh16, WhT16p, WhT16n, a16, out);
}

// Round 5
// 106.684 us; speedup vs baseline: 1.0072x; 1.0027x over previous
//
#include <hip/hip_runtime.h>

// Problem constants (B=4, N=512, D_in=512, D_out=256), fp32 in/out.
constexpr int Bq   = 4;
constexpr int Nq   = 512;
constexpr int DIN  = 512;
constexpr int DOUT = 256;

typedef _Float16 h2  __attribute__((ext_vector_type(2)));
typedef _Float16 h4  __attribute__((ext_vector_type(4)));
typedef _Float16 h8  __attribute__((ext_vector_type(8)));
typedef float    f4v __attribute__((ext_vector_type(4)));

#if defined(__has_builtin) && __has_builtin(__builtin_amdgcn_fdot2)
__device__ __forceinline__ float fdot2f(h2 a, h2 b, float c) {
    return __builtin_amdgcn_fdot2(a, b, c, false);   // v_dot2_f32_f16
}
#else
__device__ __forceinline__ float fdot2f(h2 a, h2 b, float c) {
    return (float)a.x * (float)b.x + (float)a.y * (float)b.y + c;
}
#endif

__device__ __forceinline__ h8 cvt8(float4 lo, float4 hi) {
    h8 r;
    r[0] = (_Float16)lo.x; r[1] = (_Float16)lo.y;
    r[2] = (_Float16)lo.z; r[3] = (_Float16)lo.w;
    r[4] = (_Float16)hi.x; r[5] = (_Float16)hi.y;
    r[6] = (_Float16)hi.z; r[7] = (_Float16)hi.w;
    return r;
}

// ---------------------------------------------------------------------------
// K1: Wh = H @ W^T via MFMA 16x16x32 f16, fp32->fp16 conversion in-register.
// NEW: K-split by 2 (unbundled from R3): grid 1025 x 256 thr (4 waves).
// Waves (w&1)=tile-in-block, (w>>1)=K-half; partials combined via 2 KB LDS.
// 4 waves/SIMD (was 2) and serial K-depth 8 (was 16).
// Epilogue (kh==0 waves): Wh16[n][o2] h2, WhT16p[b][o4][j] h4 (NEW o4-packed
// layout for k23's widened loads), WhT16n[b][o][j2] h4 (phase-B B-operand).
// Block 1024 converts `a`.
// ---------------------------------------------------------------------------
__global__ __launch_bounds__(256) void k1_wh(const float* __restrict__ H,
                                             const float* __restrict__ W,
                                             const float* __restrict__ a,
                                             h2* __restrict__ Wh16,
                                             h2* __restrict__ WhT16p,
                                             h2* __restrict__ WhT16n,
                                             h2* __restrict__ a16) {
    const int bid = blockIdx.x;
    const int t   = threadIdx.x;

    if (bid == 1024) {                    // a conversion (tiny, one block)
        if (t < 64) {
            const int idx = 2 * t;        // h2 index (even)
            const float4 v = *(const float4*)&a[2 * idx];
            h2 h0; h0.x = (_Float16)v.x; h0.y = (_Float16)v.y;
            h2 h1; h1.x = (_Float16)v.z; h1.y = (_Float16)v.w;
            a16[idx] = h0; a16[idx + 1] = h1;
        }
        return;
    }

    const int w    = t >> 6;
    const int lane = t & 63;
    const int T    = (bid << 1) | (w & 1);   // global tile 0..2047
    const int kh   = w >> 1;                 // K-half 0/1
    const int b    = (T >> 4) & 3;
    const int n0   = (T >> 6) << 4;          // 0..496
    const int o0   = (T & 15) << 4;          // 0..240
    const int quad = lane >> 4;
    const int col  = lane & 15;

    const float4* __restrict__ aP =
        (const float4*)(H + (size_t)(b * Nq + n0 + col) * DIN) + kh * 64 + quad * 2;
    const float4* __restrict__ bP =
        (const float4*)(W + (size_t)(o0 + col) * DIN) + kh * 64 + quad * 2;

    f4v acc = {0.f, 0.f, 0.f, 0.f};
    float4 fa0 = aP[0], fa1 = aP[1];
    float4 fb0 = bP[0], fb1 = bP[1];

#pragma unroll
    for (int kb = 0; kb < 8; ++kb) {
        float4 na0 = fa0, na1 = fa1, nb0 = fb0, nb1 = fb1;
        if (kb < 7) {                     // depth-1 prefetch
            na0 = aP[(kb + 1) * 8];
            na1 = aP[(kb + 1) * 8 + 1];
            nb0 = bP[(kb + 1) * 8];
            nb1 = bP[(kb + 1) * 8 + 1];
        }
        const h8 af = cvt8(fa0, fa1);
        const h8 bf = cvt8(fb0, fb1);
        acc = __builtin_amdgcn_mfma_f32_16x16x32_f16(af, bf, acc, 0, 0, 0);
        fa0 = na0; fa1 = na1; fb0 = nb0; fb1 = nb1;
    }

    __shared__ f4v sPart[2][64];          // per-tile K-half combine
    if (kh) sPart[w & 1][lane] = acc;
    __syncthreads();
    if (!kh) {
        const f4v p = sPart[w & 1][lane];
#pragma unroll
        for (int r = 0; r < 4; ++r) acc[r] += p[r];

        const int rloc = n0 + quad * 4;   // local row (j) of reg 0

        // j-packed transpose store (MFMA B-operand for k23 phase B), 8B/lane
        h4 hj;
        hj[0] = (_Float16)acc[0]; hj[1] = (_Float16)acc[1];
        hj[2] = (_Float16)acc[2]; hj[3] = (_Float16)acc[3];
        *(h4*)(WhT16n + ((size_t)(b * 256 + o0 + col)) * 256 + (rloc >> 1)) = hj;

        // o-packed stores (phase A operands): Wh16 h2, WhT16p h4 (o4-packed)
        h4* __restrict__ WhT16p4 = (h4*)WhT16p;
#pragma unroll
        for (int reg = 0; reg < 4; ++reg) {
            const float v  = acc[reg];
            const float vp = __shfl_xor(v, 1);    // partner o (col^1)
            h2 hv; hv.x = (_Float16)v; hv.y = (_Float16)vp;
            // pull the pair from lanes col^2 to build the o4 pack
            unsigned u;
            __builtin_memcpy(&u, &hv, 4);
            const unsigned u2 = __shfl_xor(u, 2);
            if ((col & 1) == 0) {
                const int o2 = (o0 + col) >> 1;
                Wh16[(size_t)(b * Nq + rloc + reg) * 128 + o2] = hv;       // [n][o2]
            }
            if ((col & 3) == 0) {
                h2 hv2;
                __builtin_memcpy(&hv2, &u2, 4);
                h4 q;
                q[0] = hv[0]; q[1] = hv[1]; q[2] = hv2[0]; q[3] = hv2[1];
                const int o4 = (o0 + col) >> 2;
                WhT16p4[(size_t)b * 32768 + (size_t)o4 * 512 + (rloc + reg)] = q;
            }
        }
    }
}

// ---------------------------------------------------------------------------
// K23: fused e+softmax (phase A) and out = P @ Wh (phase B, MFMA).
// Grid 512 = (b, 4 i-rows), 1024 thr, 2 blocks/CU.
// Phase A NEW: all operand streams widened 2x. wjp reads h4 (o4-packed
// WhT16p) -> 32 global loads/thread (was 64), 8-deep pipeline now covers
// ~2x the VALU per load. a16/Wh16 uniform reads via h4 s_load_dwordx2.
// VALU work identical to R4. Softmax packs P to fp16 LDS (sPh).
// Phase B: MFMA 16x16x32 f16, 16 waves x one 16-o tile (unchanged from R4).
// ---------------------------------------------------------------------------
__global__ __launch_bounds__(1024, 8) void k23(const h2* __restrict__ Wh16,
                                               const h2* __restrict__ WhT16p,
                                               const h2* __restrict__ WhT16n,
                                               const h2* __restrict__ a16,
                                               float* __restrict__ out) {
    const int t   = threadIdx.x;
    const int blk = blockIdx.x;           // 512
    const int b   = blk & 3;
    const int i0  = (blk >> 2) << 2;      // 4 i-rows

    __shared__ float smem[8192];          // 32 KB arena: sAb/sRh/sRf (A)
    __shared__ __align__(16) h2 sPh[4 * 272];   // packed P fp16, stride 272 h2
    __shared__ float wred[2][4][8];

    // ======================= Phase A: e + softmax -> sPh ===================
    {
        const int h   = __builtin_amdgcn_readfirstlane(t >> 9);  // 0/1
        const int j   = t & 511;
        const int ob4 = h * 32;           // o4 base (32 o-quads = 128 o)

        const h4* __restrict__ wjp  = (const h4*)WhT16p + (size_t)b * 32768 + j;
        const h4* __restrict__ wip4 = (const h4*)Wh16 + (size_t)(b * Nq + i0) * 64;
        const h4* __restrict__ a4p  = (const h4*)a16;

        float ab[4] = {0.f, 0.f, 0.f, 0.f};
        float rja = 0.f;                  // this half's partial of r_j
        h4 cA[8], cB[8];

#define K2_L8(buf, kb)                                                      \
    _Pragma("unroll") for (int s = 0; s < 8; ++s)                           \
        buf[s] = wjp[((size_t)(ob4 + (kb) + s)) * 512];

#define K2_C8(buf, kb)                                                      \
    _Pragma("unroll") for (int s = 0; s < 8; ++s) {                         \
        const int o4 = ob4 + (kb) + s;                                      \
        const h4 a4 = a4p[o4];                            /* s_load_x2 */   \
        const h2 alo = __builtin_shufflevector(a4, a4, 0, 1);               \
        const h2 ahi = __builtin_shufflevector(a4, a4, 2, 3);               \
        const h4 c  = buf[s];                                               \
        const h2 clo = __builtin_shufflevector(c, c, 0, 1);                 \
        const h2 chi = __builtin_shufflevector(c, c, 2, 3);                 \
        rja = fdot2f(alo, clo, rja);                                        \
        rja = fdot2f(ahi, chi, rja);                                        \
        _Pragma("unroll") for (int rr = 0; rr < 4; ++rr) {                  \
            const h4 wi = wip4[rr * 64 + o4];             /* s_load_x2 */   \
            const h2 wl = clo + __builtin_shufflevector(wi, wi, 0, 1);      \
            const h2 wh_ = chi + __builtin_shufflevector(wi, wi, 2, 3);     \
            const h2 awl = __builtin_elementwise_max(wl, -wl);              \
            const h2 awh = __builtin_elementwise_max(wh_, -wh_);            \
            ab[rr] = fdot2f(alo, awl, ab[rr]);                              \
            ab[rr] = fdot2f(ahi, awh, ab[rr]);                              \
        }                                                                   \
    }

        K2_L8(cA, 0)  K2_L8(cB, 8)
        K2_C8(cA, 0)  K2_L8(cA, 16)
        K2_C8(cB, 8)  K2_L8(cB, 24)
        K2_C8(cA, 16)
        K2_C8(cB, 24)
#undef K2_L8
#undef K2_C8

        // combine halves: sAb[4][512] @ smem[0..2047], sRh @ [2048..2559],
        // final r @ [2560..3071]
        float* sAb = smem;
        float* sRh = smem + 2048;
        float* sRf = smem + 2560;
        if (h == 1) {
#pragma unroll
            for (int rr = 0; rr < 4; ++rr) sAb[rr * 512 + j] = ab[rr];
            sRh[j] = rja;
        }
        __syncthreads();

        float rj = 0.f;
        if (h == 0) {
#pragma unroll
            for (int rr = 0; rr < 4; ++rr) ab[rr] += sAb[rr * 512 + j];
            rj = rja + sRh[j];
            sRf[j] = rj;
        }
        __syncthreads();                  // sRf visible to all

        float e[4], pv[4];
        const int lane = t & 63;
        const int w    = t >> 6;          // h0: waves 0..7

        if (h == 0) {
#pragma unroll
            for (int rr = 0; rr < 4; ++rr)
                e[rr] = 0.6f * (sRf[i0 + rr] + rj) + 0.4f * ab[rr];
#pragma unroll
            for (int rr = 0; rr < 4; ++rr) {
                float v = e[rr];
#pragma unroll
                for (int off = 32; off > 0; off >>= 1) v = fmaxf(v, __shfl_xor(v, off));
                if (lane == 0) wred[0][rr][w] = v;
            }
        }
        __syncthreads();
        if (h == 0) {
#pragma unroll
            for (int rr = 0; rr < 4; ++rr) {
                const float4 q0 = *(const float4*)&wred[0][rr][0];
                const float4 q1 = *(const float4*)&wred[0][rr][4];
                const float m = fmaxf(fmaxf(fmaxf(q0.x, q0.y), fmaxf(q0.z, q0.w)),
                                      fmaxf(fmaxf(q1.x, q1.y), fmaxf(q1.z, q1.w)));
                pv[rr] = __expf(e[rr] - m);
            }
#pragma unroll
            for (int rr = 0; rr < 4; ++rr) {
                float v = pv[rr];
#pragma unroll
                for (int off = 32; off > 0; off >>= 1) v += __shfl_xor(v, off);
                if (lane == 0) wred[1][rr][w] = v;
            }
        }
        __syncthreads();
        if (h == 0) {
#pragma unroll
            for (int rr = 0; rr < 4; ++rr) {
                const float4 q0 = *(const float4*)&wred[1][rr][0];
                const float4 q1 = *(const float4*)&wred[1][rr][4];
                const float s = (q0.x + q0.y + q0.z + q0.w) + (q1.x + q1.y + q1.z + q1.w);
                const float pn = pv[rr] * (1.0f / s);
                const float pp = __shfl_xor(pn, 1);
                if ((j & 1) == 0) {
                    h2 hv; hv.x = (_Float16)pn; hv.y = (_Float16)pp;
                    sPh[rr * 272 + (j >> 1)] = hv;     // packed along j
                }
            }
        }
        __syncthreads();                  // sPh ready
    }

    // ======================= Phase B: out = P @ Wh (MFMA) ==================
    {
        const int w16  = __builtin_amdgcn_readfirstlane(t >> 6);  // 0..15
        const int lane = t & 63;
        const int quad = lane >> 4;
        const int col  = lane & 15;
        const int o0   = w16 << 4;        // this wave's 16-o tile

        // B-frag: WhT16n row (o0+col), j2 = kb*16 + quad*4 + [0..3] (16B loads)
        const h2* __restrict__ wt =
            WhT16n + (size_t)b * 65536 + (size_t)(o0 + col) * 256 + quad * 4;
        // A-frag: packed P rows replicated (col&3) — C rows 4..15 don't-care
        const h2* __restrict__ ap = sPh + (col & 3) * 272 + quad * 4;

        f4v acc = {0.f, 0.f, 0.f, 0.f};
        h8 b0 = *(const h8*)wt;
#pragma unroll
        for (int kb = 0; kb < 16; ++kb) {
            h8 b1 = b0;
            if (kb < 15) b1 = *(const h8*)(wt + (kb + 1) * 16);   // prefetch
            const h8 af = *(const h8*)(ap + kb * 16);             // ds_read_b128
            acc = __builtin_amdgcn_mfma_f32_16x16x32_f16(af, b0, acc, 0, 0, 0);
            b0 = b1;
        }

        if (quad == 0) {                  // C rows 0..3 (i), cols = o
#pragma unroll
            for (int reg = 0; reg < 4; ++reg) {
                out[((size_t)(b * Nq) + i0 + reg) * DOUT + o0 + col] = acc[reg];
            }
        }
    }
}

// ---------------------------------------------------------------------------
extern "C" void kernel_launch(void* const* d_in, const int* in_sizes, int n_in,
                              void* d_out, int out_size, void* d_ws, size_t ws_size,
                              hipStream_t stream) {
    const float* H = (const float*)d_in[0];   // [4,512,512]
    const float* W = (const float*)d_in[1];   // [256,512]
    const float* a = (const float*)d_in[2];   // [256,1]
    float* out = (float*)d_out;               // [4,512,256]

    h2* Wh16   = (h2*)d_ws;                    // 262144 h2 (1 MB) [n][o2]
    h2* WhT16p = Wh16 + 262144;                // 131072 h4 (1 MB) [b][o4][j]
    h2* WhT16n = WhT16p + 262144;              // 262144 h2 (1 MB) [b][o][j2]
    h2* a16    = WhT16n + 262144;              // 128 h2

    hipLaunchKernelGGL(k1_wh, dim3(1025), dim3(256),  0, stream, H, W, a, Wh16, WhT16p, WhT16n, a16);
    hipLaunchKernelGGL(k23,   dim3(512),  dim3(1024), 0, stream, Wh16, WhT16p, WhT16n, a16, out);
}

// Round 7
// 105.839 us; speedup vs baseline: 1.0153x; 1.0080x over previous
//
#include <hip/hip_runtime.h>

// Problem constants (B=4, N=512, D_in=512, D_out=256), fp32 in/out.
constexpr int Bq   = 4;
constexpr int Nq   = 512;
constexpr int DIN  = 512;
constexpr int DOUT = 256;

typedef _Float16 h2  __attribute__((ext_vector_type(2)));
typedef _Float16 h4  __attribute__((ext_vector_type(4)));
typedef _Float16 h8  __attribute__((ext_vector_type(8)));
typedef float    f4v __attribute__((ext_vector_type(4)));

#if defined(__has_builtin) && __has_builtin(__builtin_amdgcn_fdot2)
__device__ __forceinline__ float fdot2f(h2 a, h2 b, float c) {
    return __builtin_amdgcn_fdot2(a, b, c, false);   // v_dot2_f32_f16
}
#else
__device__ __forceinline__ float fdot2f(h2 a, h2 b, float c) {
    return (float)a.x * (float)b.x + (float)a.y * (float)b.y + c;
}
#endif

__device__ __forceinline__ h8 cvt8(float4 lo, float4 hi) {
    h8 r;
    r[0] = (_Float16)lo.x; r[1] = (_Float16)lo.y;
    r[2] = (_Float16)lo.z; r[3] = (_Float16)lo.w;
    r[4] = (_Float16)hi.x; r[5] = (_Float16)hi.y;
    r[6] = (_Float16)hi.z; r[7] = (_Float16)hi.w;
    return r;
}

// ---------------------------------------------------------------------------
// K1 (unchanged from R5, passing): Wh = H @ W^T via MFMA 16x16x32 f16,
// fp32->fp16 cvt in-register, K-split by 2. Grid 1025 x 256 thr.
// Outputs: Wh16[n][o2] h2, WhT16p[b][o4][j] h4, WhT16n[b][o][j2] h4, a16.
// ---------------------------------------------------------------------------
__global__ __launch_bounds__(256) void k1_wh(const float* __restrict__ H,
                                             const float* __restrict__ W,
                                             const float* __restrict__ a,
                                             h2* __restrict__ Wh16,
                                             h2* __restrict__ WhT16p,
                                             h2* __restrict__ WhT16n,
                                             h2* __restrict__ a16) {
    const int bid = blockIdx.x;
    const int t   = threadIdx.x;

    if (bid == 1024) {                    // a conversion (tiny, one block)
        if (t < 64) {
            const int idx = 2 * t;        // h2 index (even)
            const float4 v = *(const float4*)&a[2 * idx];
            h2 h0; h0.x = (_Float16)v.x; h0.y = (_Float16)v.y;
            h2 h1; h1.x = (_Float16)v.z; h1.y = (_Float16)v.w;
            a16[idx] = h0; a16[idx + 1] = h1;
        }
        return;
    }

    const int w    = t >> 6;
    const int lane = t & 63;
    const int T    = (bid << 1) | (w & 1);   // global tile 0..2047
    const int kh   = w >> 1;                 // K-half 0/1
    const int b    = (T >> 4) & 3;
    const int n0   = (T >> 6) << 4;          // 0..496
    const int o0   = (T & 15) << 4;          // 0..240
    const int quad = lane >> 4;
    const int col  = lane & 15;

    const float4* __restrict__ aP =
        (const float4*)(H + (size_t)(b * Nq + n0 + col) * DIN) + kh * 64 + quad * 2;
    const float4* __restrict__ bP =
        (const float4*)(W + (size_t)(o0 + col) * DIN) + kh * 64 + quad * 2;

    f4v acc = {0.f, 0.f, 0.f, 0.f};
    float4 fa0 = aP[0], fa1 = aP[1];
    float4 fb0 = bP[0], fb1 = bP[1];

#pragma unroll
    for (int kb = 0; kb < 8; ++kb) {
        float4 na0 = fa0, na1 = fa1, nb0 = fb0, nb1 = fb1;
        if (kb < 7) {                     // depth-1 prefetch
            na0 = aP[(kb + 1) * 8];
            na1 = aP[(kb + 1) * 8 + 1];
            nb0 = bP[(kb + 1) * 8];
            nb1 = bP[(kb + 1) * 8 + 1];
        }
        const h8 af = cvt8(fa0, fa1);
        const h8 bf = cvt8(fb0, fb1);
        acc = __builtin_amdgcn_mfma_f32_16x16x32_f16(af, bf, acc, 0, 0, 0);
        fa0 = na0; fa1 = na1; fb0 = nb0; fb1 = nb1;
    }

    __shared__ f4v sPart[2][64];          // per-tile K-half combine
    if (kh) sPart[w & 1][lane] = acc;
    __syncthreads();
    if (!kh) {
        const f4v p = sPart[w & 1][lane];
#pragma unroll
        for (int r = 0; r < 4; ++r) acc[r] += p[r];

        const int rloc = n0 + quad * 4;   // local row (j) of reg 0

        // j-packed transpose store (kB phase-B B-operand), 8B/lane
        h4 hj;
        hj[0] = (_Float16)acc[0]; hj[1] = (_Float16)acc[1];
        hj[2] = (_Float16)acc[2]; hj[3] = (_Float16)acc[3];
        *(h4*)(WhT16n + ((size_t)(b * 256 + o0 + col)) * 256 + (rloc >> 1)) = hj;

        // o-packed stores (kA operands): Wh16 h2, WhT16p h4 (o4-packed)
        h4* __restrict__ WhT16p4 = (h4*)WhT16p;
#pragma unroll
        for (int reg = 0; reg < 4; ++reg) {
            const float v  = acc[reg];
            const float vp = __shfl_xor(v, 1);    // partner o (col^1)
            h2 hv; hv.x = (_Float16)v; hv.y = (_Float16)vp;
            unsigned u;
            __builtin_memcpy(&u, &hv, 4);
            const unsigned u2 = __shfl_xor(u, 2); // pair from col^2
            if ((col & 1) == 0) {
                const int o2 = (o0 + col) >> 1;
                Wh16[(size_t)(b * Nq + rloc + reg) * 128 + o2] = hv;       // [n][o2]
            }
            if ((col & 3) == 0) {
                h2 hv2;
                __builtin_memcpy(&hv2, &u2, 4);
                h4 q;
                q[0] = hv[0]; q[1] = hv[1]; q[2] = hv2[0]; q[3] = hv2[1];
                const int o4 = (o0 + col) >> 2;
                WhT16p4[(size_t)b * 32768 + (size_t)o4 * 512 + (rloc + reg)] = q;
            }
        }
    }
}

// ---------------------------------------------------------------------------
// KA: symmetric-half abs-score pass. Block = (b, i-group u of 4 rows).
// ab[i][j] = sum_o a_o |Wh_i,o + Wh_j,o| is SYMMETRIC in (i,j): each block
// computes only the cyclic half-window j in [i0+4, i0+259] (mod 512) and
// writes 0.4*ab to E at BOTH [i][j] (coalesced rows) and [j][i] (contiguous
// float4 since i is the fast axis). Window overlap at distance 64 double-
// writes bit-identical values — benign. Wave 4 computes the 4x4 diagonal
// tile; wave 5 computes r_i = a . Wh_i for the block's own 4 rows (each row
// owned by exactly one block — no atomics).
// Threads: oq = t>>8 (o-quarter, 16 o4 each), j8 = t&255. 4-way oq combine
// through 16 KB LDS. Work per block is HALF of the old phase A.
// ---------------------------------------------------------------------------
__global__ __launch_bounds__(1024, 8) void kA(const h2* __restrict__ Wh16,
                                              const h2* __restrict__ WhT16p,
                                              const h2* __restrict__ a16,
                                              float* __restrict__ E,
                                              float* __restrict__ r) {
    const int t   = threadIdx.x;
    const int blk = blockIdx.x;           // 512
    const int b   = blk & 3;
    const int u   = blk >> 2;             // 0..127
    const int i0  = u << 2;

    __shared__ float sAb[4 * 4 * 256];    // [rr][oq][j8], 16 KB

    const int oq  = __builtin_amdgcn_readfirstlane(t >> 8);   // 0..3
    const int j8  = t & 255;
    const int j   = (i0 + 4 + j8) & 511;
    const int ob0 = oq << 4;              // o4 base of this quarter

    const h4* __restrict__ wjpB = (const h4*)WhT16p + (size_t)b * 32768 + j;
    const h4* __restrict__ wip4 = (const h4*)Wh16 + (size_t)(b * Nq + i0) * 64;
    const h4* __restrict__ a4p  = (const h4*)a16;

    float ab[4] = {0.f, 0.f, 0.f, 0.f};
    h4 cA[8], cB[8];

#define KA_L8(buf, kb)                                                      \
    _Pragma("unroll") for (int s = 0; s < 8; ++s)                           \
        buf[s] = wjpB[(size_t)(ob0 + (kb) + s) * 512];

#define KA_C8(buf, kb)                                                      \
    _Pragma("unroll") for (int s = 0; s < 8; ++s) {                         \
        const int o4 = ob0 + (kb) + s;                                      \
        const h4 a4 = a4p[o4];                            /* s_load_x2 */   \
        const h2 alo = __builtin_shufflevector(a4, a4, 0, 1);               \
        const h2 ahi = __builtin_shufflevector(a4, a4, 2, 3);               \
        const h4 c  = buf[s];                                               \
        const h2 clo = __builtin_shufflevector(c, c, 0, 1);                 \
        const h2 chi = __builtin_shufflevector(c, c, 2, 3);                 \
        _Pragma("unroll") for (int rr = 0; rr < 4; ++rr) {                  \
            const h4 wi = wip4[rr * 64 + o4];             /* s_load_x2 */   \
            const h2 wl = clo + __builtin_shufflevector(wi, wi, 0, 1);      \
            const h2 wh_ = chi + __builtin_shufflevector(wi, wi, 2, 3);     \
            const h2 awl = __builtin_elementwise_max(wl, -wl);              \
            const h2 awh = __builtin_elementwise_max(wh_, -wh_);            \
            ab[rr] = fdot2f(alo, awl, ab[rr]);                              \
            ab[rr] = fdot2f(ahi, awh, ab[rr]);                              \
        }                                                                   \
    }

    KA_L8(cA, 0) KA_L8(cB, 8)
    KA_C8(cA, 0)
    KA_C8(cB, 8)
#undef KA_L8
#undef KA_C8

#pragma unroll
    for (int rr = 0; rr < 4; ++rr) sAb[(rr * 4 + oq) * 256 + j8] = ab[rr];
    __syncthreads();

    if (t < 256) {                        // combine 4 quarters + E stores
        float v[4];
#pragma unroll
        for (int rr = 0; rr < 4; ++rr)
            v[rr] = 0.4f * (sAb[(rr * 4 + 0) * 256 + t] + sAb[(rr * 4 + 1) * 256 + t] +
                            sAb[(rr * 4 + 2) * 256 + t] + sAb[(rr * 4 + 3) * 256 + t]);
        const int jj = (i0 + 4 + t) & 511;
#pragma unroll
        for (int rr = 0; rr < 4; ++rr)
            E[((size_t)(b * Nq) + i0 + rr) * 512 + jj] = v[rr];            // row-major
        float4 f;
        f.x = v[0]; f.y = v[1]; f.z = v[2]; f.w = v[3];
        *(float4*)&E[((size_t)(b * Nq) + jj) * 512 + i0] = f;              // transpose
    } else if (t < 320) {                 // wave 4: 4x4 diagonal tile
        const int l = t & 63;             // o4 = l
        const h4 a4 = a4p[l];
        const h2 alo = __builtin_shufflevector(a4, a4, 0, 1);
        const h2 ahi = __builtin_shufflevector(a4, a4, 2, 3);
        h4 wrow[4];
#pragma unroll
        for (int rr = 0; rr < 4; ++rr) wrow[rr] = wip4[rr * 64 + l];
#pragma unroll
        for (int p = 0; p < 4; ++p)
#pragma unroll
            for (int q = p; q < 4; ++q) {
                const h4 ws = wrow[p] + wrow[q];
                const h4 aw = __builtin_elementwise_max(ws, -ws);
                float s = fdot2f(alo, __builtin_shufflevector(aw, aw, 0, 1),
                          fdot2f(ahi, __builtin_shufflevector(aw, aw, 2, 3), 0.f));
#pragma unroll
                for (int off = 32; off > 0; off >>= 1) s += __shfl_xor(s, off);
                if (l == 0) {
                    const float val = 0.4f * s;
                    E[((size_t)(b * Nq) + i0 + p) * 512 + i0 + q] = val;
                    E[((size_t)(b * Nq) + i0 + q) * 512 + i0 + p] = val;
                }
            }
    } else if (t < 384) {                 // wave 5: r_i for own 4 rows
        const int l = t & 63;             // o4 = l
        const h4 a4 = a4p[l];
        const h2 alo = __builtin_shufflevector(a4, a4, 0, 1);
        const h2 ahi = __builtin_shufflevector(a4, a4, 2, 3);
#pragma unroll
        for (int rr = 0; rr < 4; ++rr) {
            const h4 wi = wip4[rr * 64 + l];
            float s = fdot2f(alo, __builtin_shufflevector(wi, wi, 0, 1),
                      fdot2f(ahi, __builtin_shufflevector(wi, wi, 2, 3), 0.f));
#pragma unroll
            for (int off = 32; off > 0; off >>= 1) s += __shfl_xor(s, off);
            if (l == 0) r[b * Nq + i0 + rr] = s;
        }
    }
}

// ---------------------------------------------------------------------------
// KB: e-assembly + softmax + out = P @ Wh (MFMA). Grid 512 = (b, i-group),
// 1024 thr. e[i][j] = 0.6*(r_i + r_j) + E[i][j]. Each 512-thread half owns
// 2 rows (all 16 waves busy in the reduces). Softmax machinery = R5's.
// Phase B MFMA verbatim R5: 16 waves x one 16-o tile, A-frag = fp16 P from
// LDS (rows replicated col&3), B-frag = 16B loads of WhT16n.
// ---------------------------------------------------------------------------
__global__ __launch_bounds__(1024, 8) void kB(const float* __restrict__ E,
                                              const float* __restrict__ r,
                                              const h2* __restrict__ WhT16n,
                                              float* __restrict__ out) {
    const int t   = threadIdx.x;
    const int blk = blockIdx.x;           // 512
    const int b   = blk & 3;
    const int i0  = (blk >> 2) << 2;      // 4 i-rows

    __shared__ __align__(16) h2 sPh[4 * 272];   // packed P fp16, stride 272 h2
    __shared__ float wred[2][4][8];

    // =================== e + softmax -> sPh ================================
    {
        const int j    = t & 511;
        const int rh   = __builtin_amdgcn_readfirstlane(t >> 9);  // 0/1
        const int lane = t & 63;
        const int w    = t >> 6;          // 0..15
        const int slot = w & 7;

        const float rj = r[b * Nq + j];
        float e[2], pv[2];
#pragma unroll
        for (int rr = 0; rr < 2; ++rr) {
            const int row = rh * 2 + rr;
            const float ri = r[b * Nq + i0 + row];                 // uniform
            e[rr] = 0.6f * (ri + rj) + E[((size_t)(b * Nq) + i0 + row) * 512 + j];
        }

#pragma unroll
        for (int rr = 0; rr < 2; ++rr) {
            float v = e[rr];
#pragma unroll
            for (int off = 32; off > 0; off >>= 1) v = fmaxf(v, __shfl_xor(v, off));
            if (lane == 0) wred[0][rh * 2 + rr][slot] = v;
        }
        __syncthreads();
#pragma unroll
        for (int rr = 0; rr < 2; ++rr) {
            const int row = rh * 2 + rr;
            const float4 q0 = *(const float4*)&wred[0][row][0];
            const float4 q1 = *(const float4*)&wred[0][row][4];
            const float m = fmaxf(fmaxf(fmaxf(q0.x, q0.y), fmaxf(q0.z, q0.w)),
                                  fmaxf(fmaxf(q1.x, q1.y), fmaxf(q1.z, q1.w)));
            pv[rr] = __expf(e[rr] - m);
            float v = pv[rr];
#pragma unroll
            for (int off = 32; off > 0; off >>= 1) v += __shfl_xor(v, off);
            if (lane == 0) wred[1][row][slot] = v;
        }
        __syncthreads();
#pragma unroll
        for (int rr = 0; rr < 2; ++rr) {
            const int row = rh * 2 + rr;
            const float4 q0 = *(const float4*)&wred[1][row][0];
            const float4 q1 = *(const float4*)&wred[1][row][4];
            const float s = (q0.x + q0.y + q0.z + q0.w) + (q1.x + q1.y + q1.z + q1.w);
            const float pn = pv[rr] * (1.0f / s);
            const float pp = __shfl_xor(pn, 1);
            if ((j & 1) == 0) {
                h2 hv; hv.x = (_Float16)pn; hv.y = (_Float16)pp;
                sPh[row * 272 + (j >> 1)] = hv;        // packed along j
            }
        }
        __syncthreads();                  // sPh ready
    }

    // =================== out = P @ Wh (MFMA) ===============================
    {
        const int w16  = __builtin_amdgcn_readfirstlane(t >> 6);  // 0..15
        const int lane = t & 63;
        const int quad = lane >> 4;
        const int col  = lane & 15;
        const int o0   = w16 << 4;        // this wave's 16-o tile

        const h2* __restrict__ wt =
            WhT16n + (size_t)b * 65536 + (size_t)(o0 + col) * 256 + quad * 4;
        const h2* __restrict__ ap = sPh + (col & 3) * 272 + quad * 4;

        f4v acc = {0.f, 0.f, 0.f, 0.f};
        h8 b0 = *(const h8*)wt;
#pragma unroll
        for (int kb = 0; kb < 16; ++kb) {
            h8 b1 = b0;
            if (kb < 15) b1 = *(const h8*)(wt + (kb + 1) * 16);   // prefetch
            const h8 af = *(const h8*)(ap + kb * 16);             // ds_read_b128
            acc = __builtin_amdgcn_mfma_f32_16x16x32_f16(af, b0, acc, 0, 0, 0);
            b0 = b1;
        }

        if (quad == 0) {                  // C rows 0..3 (i), cols = o
#pragma unroll
            for (int reg = 0; reg < 4; ++reg) {
                out[((size_t)(b * Nq) + i0 + reg) * DOUT + o0 + col] = acc[reg];
            }
        }
    }
}

// ---------------------------------------------------------------------------
extern "C" void kernel_launch(void* const* d_in, const int* in_sizes, int n_in,
                              void* d_out, int out_size, void* d_ws, size_t ws_size,
                              hipStream_t stream) {
    const float* H = (const float*)d_in[0];   // [4,512,512]
    const float* W = (const float*)d_in[1];   // [256,512]
    const float* a = (const float*)d_in[2];   // [256,1]
    float* out = (float*)d_out;               // [4,512,256]

    h2* Wh16   = (h2*)d_ws;                    // 262144 h2 (1 MB) [n][o2]
    h2* WhT16p = Wh16 + 262144;                // 131072 h4 (1 MB) [b][o4][j]
    h2* WhT16n = WhT16p + 262144;              // 262144 h2 (1 MB) [b][o][j2]
    h2* a16    = WhT16n + 262144;              // 128 h2
    float* E   = (float*)(a16 + 128);          // [4][512][512] fp32 (4 MB)
    float* r   = E + (size_t)Bq * Nq * Nq / Nq * Nq; // see below (kept simple)

    // r placed right after E: E has 4*512*512 = 1048576 floats
    r = E + 1048576;                           // [4][512] fp32 (8 KB)

    hipLaunchKernelGGL(k1_wh, dim3(1025), dim3(256),  0, stream, H, W, a, Wh16, WhT16p, WhT16n, a16);
    hipLaunchKernelGGL(kA,    dim3(512),  dim3(1024), 0, stream, Wh16, WhT16p, a16, E, r);
    hipLaunchKernelGGL(kB,    dim3(512),  dim3(1024), 0, stream, E, r, WhT16n, out);
}